// Round 2
// baseline (272.293 us; speedup 1.0000x reference)
//
#include <hip/hip_runtime.h>
#include <hip/hip_bf16.h>
#include <cstdint>

#define BB   4
#define SENC 2048
#define SDEC 1024
#define DM   1024
#define NH   16
#define HD   64

using short8 = __attribute__((ext_vector_type(8))) short;
using f32x4  = __attribute__((ext_vector_type(4))) float;

// round-half-up fp32 -> bf16 (2 VALU ops)
__device__ inline unsigned short f2bf(float f) {
    return (unsigned short)((__builtin_bit_cast(unsigned int, f) + 0x8000u) >> 16);
}
// pack two fp32 -> bf16x2 dword
__device__ inline unsigned int pk2bf(float a, float b) {
    return ((__builtin_bit_cast(unsigned int, a) + 0x8000u) >> 16) |
           ((__builtin_bit_cast(unsigned int, b) + 0x8000u) & 0xffff0000u);
}

__device__ inline float fexp2(float x) {
#if __has_builtin(__builtin_amdgcn_exp2f)
    return __builtin_amdgcn_exp2f(x);
#else
    return exp2f(x);
#endif
}

#if __has_builtin(__builtin_amdgcn_global_load_lds)
#define HAS_GLL 1
#endif

__device__ inline void stage16(const void* g, void* l) {
#ifdef HAS_GLL
    typedef __attribute__((address_space(1))) const unsigned int guint;
    typedef __attribute__((address_space(3))) unsigned int luint;
    __builtin_amdgcn_global_load_lds((guint*)g, (luint*)l, 16, 0, 0);
#else
    *(short8*)l = *(const short8*)g;
#endif
}

// ---------------- fused prep: activation convert + weight transpose to fragment-major ----------------
// blocks [0,12288): fp32->bf16 convert of dec (4M) then enc (8M) into contiguous actb
// blocks [12288,13312): W[K,N] fp32 -> W'[n/16][k/8][n%16][k%8] bf16 (MFMA-B-fragment-major)
__global__ __launch_bounds__(256) void prep_kernel(
    const float* __restrict__ dec, const float* __restrict__ enc,
    unsigned short* __restrict__ actb,
    const float* __restrict__ qw, const float* __restrict__ kw,
    const float* __restrict__ vw, const float* __restrict__ ow,
    unsigned short* __restrict__ qwt, unsigned short* __restrict__ kvwt,
    unsigned short* __restrict__ owt) {
    __shared__ float t[64][65];
    const int id = blockIdx.x, tid = threadIdx.x;
    if (id < 12288) {
        const int nd = BB * SDEC * DM;  // 4M
        int i = (id * 256 + tid) * 4;
        const float* src = (i < nd) ? (dec + i) : (enc + (i - nd));
        float4 v = *(const float4*)src;
        ushort4 o;
        o.x = f2bf(v.x); o.y = f2bf(v.y); o.z = f2bf(v.z); o.w = f2bf(v.w);
        *(ushort4*)(actb + i) = o;
        return;
    }
    const int id2 = id - 12288;
    const int z = id2 >> 8, ky = (id2 >> 4) & 15, nx = id2 & 15;
    const float* src; unsigned short* dst;
    switch (z) {
        case 0:  src = qw; dst = qwt; break;
        case 1:  src = kw; dst = kvwt; break;
        case 2:  src = vw; dst = kvwt + (size_t)64 * 16384; break;  // second 1024 n-rows
        default: src = ow; dst = owt; break;
    }
    const int k0 = ky * 64, n0 = nx * 64;
    #pragma unroll
    for (int it = 0; it < 16; ++it) {
        int e = it * 256 + tid, r = e >> 6, c = e & 63;  // r = local k, c = local n
        t[r][c] = src[(size_t)(k0 + r) * DM + n0 + c];
    }
    __syncthreads();
    #pragma unroll
    for (int it = 0; it < 16; ++it) {
        int e = it * 256 + tid, r = e >> 6, c = e & 63;  // r = local n, c = local k
        // element (n = n0+r, k = k0+c) -> fragment-major
        size_t off = (size_t)((n0 + r) >> 4) * 16384 + (size_t)((k0 + c) >> 3) * 128
                   + ((r & 15) << 3) + (c & 7);
        dst[off] = f2bf(t[c][r]);
    }
}

// ---------------- fused Q/K/V projection GEMM : 8-wave 256x128 tile, 2-phase/K-tile schedule ----------
// T2: XOR-swizzled A in LDS (linear global_load_lds dest + inverse-swizzled global source,
//     swizzled ds_read -> conflict-free b128). T3/T4: per-phase {ds_read || issue -> s_barrier ->
//     16 MFMA}, counted vmcnt(8) per K-tile (never 0 in main loop). T5: setprio around MFMA.
// B (weights) streamed DIRECT from global fragment-major into registers, depth-1 prefetch
// (compiler inserts exact counted waits for these ordinary loads).
// blocks [0,512):   encb[8192,1024] @ kvW'^T -> K / V^T (frag-major per bh)
// blocks [512,640): decb[4096,1024] @ qW'^T  -> Q ([b,h,sq,d] row-major, scaled)
#define FENCE() asm volatile("" ::: "memory")
#define BARRIER() do { FENCE(); __builtin_amdgcn_s_barrier(); FENCE(); } while (0)

#define STAGE_TILE(kt, bufi) do { \
    stage16(Ab + (kt) * 64,          &As[bufi][tid * 8]); \
    stage16(Ab + 65536 + (kt) * 64,  &As[bufi][4096 + tid * 8]); \
    stage16(Ab + 131072 + (kt) * 64, &As[bufi][8192 + tid * 8]); \
    stage16(Ab + 196608 + (kt) * 64, &As[bufi][12288 + tid * 8]); \
} while (0)

#define LOADB(dst, kt) do { \
    dst[0][0] = *(const short8*)&Bbase[(kt) * 1024]; \
    dst[0][1] = *(const short8*)&Bbase[(kt) * 1024 + 512]; \
    dst[1][0] = *(const short8*)&Bbase[16384 + (kt) * 1024]; \
    dst[1][1] = *(const short8*)&Bbase[16384 + (kt) * 1024 + 512]; \
    dst[2][0] = *(const short8*)&Bbase[32768 + (kt) * 1024]; \
    dst[2][1] = *(const short8*)&Bbase[32768 + (kt) * 1024 + 512]; \
    dst[3][0] = *(const short8*)&Bbase[49152 + (kt) * 1024]; \
    dst[3][1] = *(const short8*)&Bbase[49152 + (kt) * 1024 + 512]; \
} while (0)

#define MFMA8(ii, a0, a1) do { \
    acc[ii][0] = __builtin_amdgcn_mfma_f32_16x16x32_bf16(a0, bcur[0][0], acc[ii][0], 0, 0, 0); \
    acc[ii][1] = __builtin_amdgcn_mfma_f32_16x16x32_bf16(a0, bcur[1][0], acc[ii][1], 0, 0, 0); \
    acc[ii][2] = __builtin_amdgcn_mfma_f32_16x16x32_bf16(a0, bcur[2][0], acc[ii][2], 0, 0, 0); \
    acc[ii][3] = __builtin_amdgcn_mfma_f32_16x16x32_bf16(a0, bcur[3][0], acc[ii][3], 0, 0, 0); \
    acc[ii][0] = __builtin_amdgcn_mfma_f32_16x16x32_bf16(a1, bcur[0][1], acc[ii][0], 0, 0, 0); \
    acc[ii][1] = __builtin_amdgcn_mfma_f32_16x16x32_bf16(a1, bcur[1][1], acc[ii][1], 0, 0, 0); \
    acc[ii][2] = __builtin_amdgcn_mfma_f32_16x16x32_bf16(a1, bcur[2][1], acc[ii][2], 0, 0, 0); \
    acc[ii][3] = __builtin_amdgcn_mfma_f32_16x16x32_bf16(a1, bcur[3][1], acc[ii][3], 0, 0, 0); \
} while (0)

__global__ __launch_bounds__(512, 2) void gemm_qkv_kernel(
    const unsigned short* __restrict__ encb, const unsigned short* __restrict__ decb,
    const unsigned short* __restrict__ kvwt, const unsigned short* __restrict__ qwt,
    const float* __restrict__ q_b, const float* __restrict__ k_b, const float* __restrict__ v_b,
    unsigned short* __restrict__ Qb, unsigned short* __restrict__ Kb,
    unsigned short* __restrict__ Vtb) {
    __shared__ __align__(16) unsigned short As[2][256 * 64];   // 64 KiB, double-buffered K-tiles
    const int id = blockIdx.x;
    const bool isKV = id < 512;
    const unsigned short *A, *Bw;
    int m0, n0;
    if (isKV) {
        const int x = id & 7, w = id >> 3;     // XCD-aware: id&7 -> m superpanel
        A = encb; Bw = kvwt;
        m0 = (x * 4 + (w >> 4)) * 256;         // 32 m-tiles of 256
        n0 = (w & 15) * 128;                   // 16 n-tiles of 128
    } else {
        const int i2 = id - 512, x = i2 & 7, w = i2 >> 3;
        A = decb; Bw = qwt;
        m0 = (x * 2 + (w >> 3)) * 256;         // 16 m-tiles
        n0 = (w & 7) * 128;                    // 8 n-tiles
    }
    const int tid = threadIdx.x;
    const int wave = tid >> 6, lane = tid & 63, quad = lane >> 4, l16 = lane & 15;
    const int wr = wave >> 1, wc = wave & 1;   // 4x2 wave grid, 64x64 per wave
    f32x4 acc[4][4] = {};

    // staging: chunk c covers rows [c*64, c*64+64); linear LDS dest = (c*512+tid)*16B;
    // inverse-swizzled global k source so that ds_read with byte^((row&7)<<4) is logical.
    const int srow = tid >> 3;
    const int ksrc = ((tid ^ srow) & 7) * 8;
    const unsigned short* Ab = A + (size_t)(m0 + srow) * 1024 + ksrc;

    // B fragment base (fragment-major [n/16][k/8][n%16][k%8])
    const unsigned short* Bbase = Bw + (size_t)((n0 >> 4) + wc * 4) * 16384 + quad * 128 + l16 * 8;
    short8 bcur[4][2], bnxt[4][2];

    // swizzled LDS read offsets (bytes): af(i,kc) at rbase + i*2048 + ((kc*64+quad*16) ^ rswz)
    const int rbase = (wr * 64 + l16) * 128;
    const int rswz = (l16 & 7) << 4;
    const int rk0 = (quad * 16) ^ rswz;
    const int rk1 = (64 + quad * 16) ^ rswz;

    // ---------------- prologue: tiles 0,1 staged; B(0) in regs ----------------
    STAGE_TILE(0, 0);
    FENCE();
    LOADB(bcur, 0);
    FENCE();
    STAGE_TILE(1, 1);
    FENCE();
    asm volatile("s_waitcnt vmcnt(12)" ::: "memory");  // st(0)+B(0) done; st(1) may fly
    __builtin_amdgcn_s_barrier();
    FENCE();

    // ---------------- main loop: tiles 0..14 (tile 15 peeled, no issues) ----------------
    #pragma unroll
    for (int kt = 0; kt <= 14; ++kt) {
        const char* ap = (const char*)&As[kt & 1][0] + rbase;
        // ---- phase 0 : ds_read i=0,1 ; issue stage(kt+1)+B(kt+1) ; barrier ; 16 MFMA ----
        short8 a00 = *(const short8*)(ap + rk0);
        short8 a01 = *(const short8*)(ap + rk1);
        short8 a10 = *(const short8*)(ap + 2048 + rk0);
        short8 a11 = *(const short8*)(ap + 2048 + rk1);
        if (kt >= 1) {                       // tile1 already staged in prologue
            STAGE_TILE(kt + 1, (kt & 1) ^ 1);
            FENCE();
        }
        LOADB(bnxt, kt + 1);
        FENCE();
        __builtin_amdgcn_s_barrier();
        FENCE();
        __builtin_amdgcn_s_setprio(1);
        MFMA8(0, a00, a01);
        MFMA8(1, a10, a11);
        __builtin_amdgcn_s_setprio(0);
        BARRIER();
        // ---- phase 1 : ds_read i=2,3 ; barrier ; 16 MFMA ; counted vmcnt ; barrier ----
        short8 a20 = *(const short8*)(ap + 4096 + rk0);
        short8 a21 = *(const short8*)(ap + 4096 + rk1);
        short8 a30 = *(const short8*)(ap + 6144 + rk0);
        short8 a31 = *(const short8*)(ap + 6144 + rk1);
        FENCE();
        __builtin_amdgcn_s_barrier();
        FENCE();
        __builtin_amdgcn_s_setprio(1);
        MFMA8(2, a20, a21);
        MFMA8(3, a30, a31);
        __builtin_amdgcn_s_setprio(0);
        asm volatile("s_waitcnt vmcnt(8)" ::: "memory");  // stages of kt+1 done; 8 B-loads fly
        __builtin_amdgcn_s_barrier();
        FENCE();
        bcur[0][0] = bnxt[0][0]; bcur[0][1] = bnxt[0][1];
        bcur[1][0] = bnxt[1][0]; bcur[1][1] = bnxt[1][1];
        bcur[2][0] = bnxt[2][0]; bcur[2][1] = bnxt[2][1];
        bcur[3][0] = bnxt[3][0]; bcur[3][1] = bnxt[3][1];
    }
    // ---- tile 15 ----
    {
        const char* ap = (const char*)&As[1][0] + rbase;
        short8 a00 = *(const short8*)(ap + rk0);
        short8 a01 = *(const short8*)(ap + rk1);
        short8 a10 = *(const short8*)(ap + 2048 + rk0);
        short8 a11 = *(const short8*)(ap + 2048 + rk1);
        __builtin_amdgcn_s_setprio(1);
        MFMA8(0, a00, a01);
        MFMA8(1, a10, a11);
        __builtin_amdgcn_s_setprio(0);
        short8 a20 = *(const short8*)(ap + 4096 + rk0);
        short8 a21 = *(const short8*)(ap + 4096 + rk1);
        short8 a30 = *(const short8*)(ap + 6144 + rk0);
        short8 a31 = *(const short8*)(ap + 6144 + rk1);
        __builtin_amdgcn_s_setprio(1);
        MFMA8(2, a20, a21);
        MFMA8(3, a30, a31);
        __builtin_amdgcn_s_setprio(0);
    }

    // ---------------- epilogue (layouts unchanged) ----------------
    #pragma unroll
    for (int i = 0; i < 4; ++i) {
        #pragma unroll
        for (int j = 0; j < 4; ++j) {
            const int gc = n0 + wc * 64 + j * 16 + l16;
            const int gr0 = m0 + wr * 64 + i * 16 + quad * 4;
            if (!isKV) {
                const float bv = q_b[gc];
                const int h = gc >> 6, d = gc & 63;
                #pragma unroll
                for (int rr = 0; rr < 4; ++rr) {
                    int gr = gr0 + rr, b = gr >> 10, sq = gr & 1023;
                    float v = (acc[i][j][rr] + bv) * 0.18033688011112042f;  // 1/(8 ln2)
                    Qb[(((size_t)(b * NH + h) * SDEC + sq) << 6) + d] = f2bf(v);
                }
            } else if (gc < 1024) {
                // K fragment-major per bh: [sk/16][d/8][sk%16][d%8]
                const float bv = k_b[gc];
                const int h = gc >> 6, d = gc & 63;
                #pragma unroll
                for (int rr = 0; rr < 4; ++rr) {
                    int gr = gr0 + rr, b = gr >> 11, sk = gr & 2047;
                    size_t off = (size_t)(b * NH + h) * 131072 + (size_t)(sk >> 4) * 1024
                               + ((d >> 3) << 7) + ((sk & 15) << 3) + (d & 7);
                    Kb[off] = f2bf(acc[i][j][rr] + bv);
                }
            } else {
                // V^T fragment-major per bh: [d/16][key/8][d%16][key%8]; 4 consecutive keys -> 8B store
                const int gc2 = gc & 1023;
                const float bv = v_b[gc2];
                const int h = gc2 >> 6, d = gc2 & 63;
                const int b = gr0 >> 11, sk0 = gr0 & 2047;
                size_t off = (size_t)(b * NH + h) * 131072 + (size_t)(d >> 4) * 32768
                           + (size_t)(sk0 >> 3) * 128 + ((d & 15) << 3) + (sk0 & 7);
                uint2 pk;
                pk.x = pk2bf(acc[i][j][0] + bv, acc[i][j][1] + bv);
                pk.y = pk2bf(acc[i][j][2] + bv, acc[i][j][3] + bv);
                *(uint2*)&Vtb[off] = pk;
            }
        }
    }
}

// ---------------- output projection GEMM: out[4096,1024] fp32; B direct, XCD swizzle ----------------
__global__ __launch_bounds__(256) void gemm_o_kernel(const unsigned short* __restrict__ A,
                                                     const unsigned short* __restrict__ Bw,
                                                     const float* __restrict__ bias,
                                                     float* __restrict__ Cout) {
    __shared__ __align__(16) unsigned short As[2][64 * 32];
    const int id = blockIdx.x, x = id & 7, w = id >> 3;
    const int m0 = (x * 8 + (w >> 3)) * 64, n0 = (w & 7) * 128;
    const int tid = threadIdx.x;
    const int wave = tid >> 6, lane = tid & 63, quad = lane >> 4, l16 = lane & 15;
    const int r16 = lane >> 2, c8 = (lane & 3) * 8;
    f32x4 acc[4][2] = {};
    const unsigned short* Bbase = Bw + (size_t)((n0 >> 4) + wave * 2) * 16384 + quad * 128 + l16 * 8;
    short8 bcur[2], bnxt[2];
    #pragma unroll
    for (int j = 0; j < 2; ++j) bcur[j] = *(const short8*)&Bbase[j * 16384];
    {
        const int rowA = wave * 16 + r16;
        stage16(&A[(size_t)(m0 + rowA) * DM + c8], &As[0][rowA * 32 + c8]);
    }
    for (int it = 0; it < 32; ++it) {
        const int bf = it & 1;
        __syncthreads();
        if (it < 31) {
            const int kb2 = (it + 1) * 32, nb = bf ^ 1;
            const int rowA = wave * 16 + r16;
            stage16(&A[(size_t)(m0 + rowA) * DM + kb2 + c8], &As[nb][rowA * 32 + c8]);
            #pragma unroll
            for (int j = 0; j < 2; ++j) bnxt[j] = *(const short8*)&Bbase[j * 16384 + kb2 * 16];
        }
        short8 af[4];
        #pragma unroll
        for (int i = 0; i < 4; ++i) af[i] = *(const short8*)&As[bf][(i * 16 + l16) * 32 + quad * 8];
        #pragma unroll
        for (int i = 0; i < 4; ++i)
            #pragma unroll
            for (int j = 0; j < 2; ++j)
                acc[i][j] = __builtin_amdgcn_mfma_f32_16x16x32_bf16(af[i], bcur[j], acc[i][j], 0, 0, 0);
        #pragma unroll
        for (int j = 0; j < 2; ++j) bcur[j] = bnxt[j];
    }
    #pragma unroll
    for (int i = 0; i < 4; ++i)
        #pragma unroll
        for (int j = 0; j < 2; ++j) {
            const int gc = n0 + wave * 32 + j * 16 + l16;
            const float bv = bias[gc];
            #pragma unroll
            for (int rr = 0; rr < 4; ++rr) {
                const int gr = m0 + i * 16 + quad * 4 + rr;
                Cout[(size_t)gr * DM + gc] = acc[i][j][rr] + bv;
            }
        }
}

// ---------------- flash cross-attention: barrier-free, direct fragment loads ----------------
__global__ __launch_bounds__(256) void attn_kernel(const unsigned short* __restrict__ Qb,
                                                   const unsigned short* __restrict__ Kb,
                                                   const unsigned short* __restrict__ Vtb,
                                                   const int* __restrict__ mask,
                                                   unsigned short* __restrict__ Xb) {
    __shared__ __align__(16) unsigned short Ps[4][16 * 72];
    const int id = blockIdx.x, x = id & 7, r = id >> 3;
    const int bh = x * 8 + (r & 7), qt = r >> 3;
    const int b = bh >> 4, h = bh & 15;
    const int q0 = qt * 128;
    const int tid = threadIdx.x, wave = tid >> 6, lane = tid & 63;
    const int quad = lane >> 4, l16 = lane & 15;
    const int lo = quad * 128 + l16 * 8;  // shared lane offset for kA/vB fragment loads

    const unsigned short* Kfp = Kb + (size_t)bh * 131072;
    const unsigned short* Vfp = Vtb + (size_t)bh * 131072;
    const int* mp = mask + (size_t)b * SENC;

    short8 qf[2][2];  // B-operand: query n = l16 within group g
    {
        const unsigned short* Qp = Qb + ((size_t)bh * SDEC + q0 + wave * 32) * HD;
        #pragma unroll
        for (int g = 0; g < 2; ++g) {
            qf[g][0] = *(const short8*)&Qp[(g * 16 + l16) * HD + quad * 8];
            qf[g][1] = *(const short8*)&Qp[(g * 16 + l16) * HD + 32 + quad * 8];
        }
    }

    float lsum[2] = {0.f, 0.f};
    f32x4 o[2][4] = {};

    for (int kb = 0; kb < SENC; kb += 64) {
        short8 kA0[4], kA1[4], vB0[4], vB1[4];
        const unsigned short* kt = Kfp + (size_t)(kb >> 4) * 1024 + lo;
        const unsigned short* vt = Vfp + (size_t)(kb >> 3) * 128 + lo;
        #pragma unroll
        for (int j = 0; j < 4; ++j) {
            kA0[j] = *(const short8*)&kt[j * 1024];
            kA1[j] = *(const short8*)&kt[j * 1024 + 512];
            vB0[j] = *(const short8*)&vt[j * 32768];
            vB1[j] = *(const short8*)&vt[j * 32768 + 512];
        }
        int4 mi[4];
        #pragma unroll
        for (int j = 0; j < 4; ++j) mi[j] = *(const int4*)&mp[kb + j * 16 + quad * 4];
        #pragma unroll
        for (int g = 0; g < 2; ++g) {
            f32x4 st[4];
            #pragma unroll
            for (int j = 0; j < 4; ++j) {
                f32x4 z = {0.f, 0.f, 0.f, 0.f};
                z = __builtin_amdgcn_mfma_f32_16x16x32_bf16(kA0[j], qf[g][0], z, 0, 0, 0);
                st[j] = __builtin_amdgcn_mfma_f32_16x16x32_bf16(kA1[j], qf[g][1], z, 0, 0, 0);
            }
            #pragma unroll
            for (int j = 0; j < 4; ++j) {
                float p0 = mi[j].x ? 0.f : fexp2(st[j][0]);
                float p1 = mi[j].y ? 0.f : fexp2(st[j][1]);
                float p2 = mi[j].z ? 0.f : fexp2(st[j][2]);
                float p3 = mi[j].w ? 0.f : fexp2(st[j][3]);
                lsum[g] += (p0 + p1) + (p2 + p3);
                uint2 pkv;
                pkv.x = pk2bf(p0, p1);
                pkv.y = pk2bf(p2, p3);
                *(uint2*)&Ps[wave][l16 * 72 + j * 16 + quad * 4] = pkv;
            }
            asm volatile("s_waitcnt lgkmcnt(0)" ::: "memory");  // Ps write->read, same wave
            short8 pA0 = *(const short8*)&Ps[wave][l16 * 72 + quad * 8];
            short8 pA1 = *(const short8*)&Ps[wave][l16 * 72 + 32 + quad * 8];
            #pragma unroll
            for (int dj = 0; dj < 4; ++dj) {
                o[g][dj] = __builtin_amdgcn_mfma_f32_16x16x32_bf16(pA0, vB0[dj], o[g][dj], 0, 0, 0);
                o[g][dj] = __builtin_amdgcn_mfma_f32_16x16x32_bf16(pA1, vB1[dj], o[g][dj], 0, 0, 0);
            }
        }
    }
    #pragma unroll
    for (int g = 0; g < 2; ++g) {
        float lg = lsum[g];
        lg += __shfl_xor(lg, 16);
        lg += __shfl_xor(lg, 32);
        #pragma unroll
        for (int rr = 0; rr < 4; ++rr) {
            float iv = 1.0f / __shfl(lg, quad * 4 + rr, 64);
            int sq = q0 + wave * 32 + g * 16 + quad * 4 + rr;
            #pragma unroll
            for (int dj = 0; dj < 4; ++dj)
                Xb[((size_t)(b * SDEC) + sq) * DM + h * HD + dj * 16 + l16] = f2bf(o[g][dj][rr] * iv);
        }
    }
}

extern "C" void kernel_launch(void* const* d_in, const int* in_sizes, int n_in,
                              void* d_out, int out_size, void* d_ws, size_t ws_size,
                              hipStream_t stream) {
    const float* enc   = (const float*)d_in[0];
    const int*   emask = (const int*)d_in[1];
    const float* dec   = (const float*)d_in[2];
    const float* q_w   = (const float*)d_in[3];
    const float* q_b   = (const float*)d_in[4];
    const float* k_w   = (const float*)d_in[5];
    const float* k_b   = (const float*)d_in[6];
    const float* v_w   = (const float*)d_in[7];
    const float* v_b   = (const float*)d_in[8];
    const float* o_w   = (const float*)d_in[9];
    const float* o_b   = (const float*)d_in[10];
    float* out = (float*)d_out;

    char* ws = (char*)d_ws;
    unsigned short* decb = (unsigned short*)ws; ws += (size_t)4096 * 1024 * 2;  // dec||enc contiguous
    unsigned short* encb = (unsigned short*)ws; ws += (size_t)8192 * 1024 * 2;
    unsigned short* qwt  = (unsigned short*)ws; ws += (size_t)1024 * 1024 * 2;
    unsigned short* kvwt = (unsigned short*)ws; ws += (size_t)2048 * 1024 * 2;
    unsigned short* owt  = (unsigned short*)ws; ws += (size_t)1024 * 1024 * 2;
    unsigned short* Qb   = (unsigned short*)ws; ws += (size_t)BB * NH * SDEC * HD * 2;
    unsigned short* Kb   = (unsigned short*)ws; ws += (size_t)BB * NH * SENC * HD * 2;
    unsigned short* Vtb  = (unsigned short*)ws; ws += (size_t)BB * NH * HD * SENC * 2;
    unsigned short* Xb   = (unsigned short*)ws; ws += (size_t)4096 * 1024 * 2;

    prep_kernel<<<13312, 256, 0, stream>>>(dec, enc, decb, q_w, k_w, v_w, o_w, qwt, kvwt, owt);
    gemm_qkv_kernel<<<640, 512, 0, stream>>>(encb, decb, kvwt, qwt, q_b, k_b, v_b, Qb, Kb, Vtb);
    attn_kernel<<<512, 256, 0, stream>>>(Qb, Kb, Vtb, emask, Xb);
    gemm_o_kernel<<<512, 256, 0, stream>>>(Xb, owt, o_b, out);
}

// Round 3
// 261.514 us; speedup vs baseline: 1.0412x; 1.0412x over previous
//
#include <hip/hip_runtime.h>
#include <hip/hip_bf16.h>
#include <cstdint>

#define BB   4
#define SENC 2048
#define SDEC 1024
#define DM   1024
#define NH   16
#define HD   64

using short8 = __attribute__((ext_vector_type(8))) short;
using f32x4  = __attribute__((ext_vector_type(4))) float;

// round-half-up fp32 -> bf16 (2 VALU ops)
__device__ inline unsigned short f2bf(float f) {
    return (unsigned short)((__builtin_bit_cast(unsigned int, f) + 0x8000u) >> 16);
}
// pack two fp32 -> bf16x2 dword
__device__ inline unsigned int pk2bf(float a, float b) {
    return ((__builtin_bit_cast(unsigned int, a) + 0x8000u) >> 16) |
           ((__builtin_bit_cast(unsigned int, b) + 0x8000u) & 0xffff0000u);
}

__device__ inline float fexp2(float x) {
#if __has_builtin(__builtin_amdgcn_exp2f)
    return __builtin_amdgcn_exp2f(x);
#else
    return exp2f(x);
#endif
}

#if __has_builtin(__builtin_amdgcn_global_load_lds)
#define HAS_GLL 1
#endif

__device__ inline void stage16(const void* g, void* l) {
#ifdef HAS_GLL
    typedef __attribute__((address_space(1))) const unsigned int guint;
    typedef __attribute__((address_space(3))) unsigned int luint;
    __builtin_amdgcn_global_load_lds((guint*)g, (luint*)l, 16, 0, 0);
#else
    *(short8*)l = *(const short8*)g;
#endif
}

// ---------------- fused prep: activation convert + weight transpose to fragment-major ----------------
// blocks [0,12288): fp32->bf16 convert of dec (4M) then enc (8M) into contiguous actb
// blocks [12288,13312): W[K,N] fp32 -> W'[n/16][k/8][n%16][k%8] bf16 (MFMA-B-fragment-major)
__global__ __launch_bounds__(256) void prep_kernel(
    const float* __restrict__ dec, const float* __restrict__ enc,
    unsigned short* __restrict__ actb,
    const float* __restrict__ qw, const float* __restrict__ kw,
    const float* __restrict__ vw, const float* __restrict__ ow,
    unsigned short* __restrict__ qwt, unsigned short* __restrict__ kvwt,
    unsigned short* __restrict__ owt) {
    __shared__ float t[64][65];
    const int id = blockIdx.x, tid = threadIdx.x;
    if (id < 12288) {
        const int nd = BB * SDEC * DM;  // 4M
        int i = (id * 256 + tid) * 4;
        const float* src = (i < nd) ? (dec + i) : (enc + (i - nd));
        float4 v = *(const float4*)src;
        ushort4 o;
        o.x = f2bf(v.x); o.y = f2bf(v.y); o.z = f2bf(v.z); o.w = f2bf(v.w);
        *(ushort4*)(actb + i) = o;
        return;
    }
    const int id2 = id - 12288;
    const int z = id2 >> 8, ky = (id2 >> 4) & 15, nx = id2 & 15;
    const float* src; unsigned short* dst;
    switch (z) {
        case 0:  src = qw; dst = qwt; break;
        case 1:  src = kw; dst = kvwt; break;
        case 2:  src = vw; dst = kvwt + (size_t)64 * 16384; break;  // second 1024 n-rows
        default: src = ow; dst = owt; break;
    }
    const int k0 = ky * 64, n0 = nx * 64;
    #pragma unroll
    for (int it = 0; it < 16; ++it) {
        int e = it * 256 + tid, r = e >> 6, c = e & 63;  // r = local k, c = local n
        t[r][c] = src[(size_t)(k0 + r) * DM + n0 + c];
    }
    __syncthreads();
    #pragma unroll
    for (int it = 0; it < 16; ++it) {
        int e = it * 256 + tid, r = e >> 6, c = e & 63;  // r = local n, c = local k
        // element (n = n0+r, k = k0+c) -> fragment-major
        size_t off = (size_t)((n0 + r) >> 4) * 16384 + (size_t)((k0 + c) >> 3) * 128
                   + ((r & 15) << 3) + (c & 7);
        dst[off] = f2bf(t[c][r]);
    }
}

// ---------------- fused Q/K/V projection GEMM : 256x128 tile, BK=64, depth-2 counted pipeline -------
// Both A and B staged via global_load_lds into TRIPLE-buffered LDS (144 KB): during tile kt we stage
// tile kt+2, so the per-tile counted wait vmcnt(6) drains stage(kt+1) while stage(kt+2)'s 6 ops stay
// in flight (never vmcnt(0) in main loop). No register-load dependencies inside the loop -> no
// compiler-inserted full drains (round-2's failure). A keeps the verified XOR swizzle; B is
// fragment-major so staging AND reads are contiguous/conflict-free.
// blocks [0,512):   encb[8192,1024] @ kvW'^T -> K / V^T (frag-major per bh)
// blocks [512,640): decb[4096,1024] @ qW'^T  -> Q ([b,h,sq,d] row-major, scaled)
#define FENCE() asm volatile("" ::: "memory")
#define BARRIER() do { FENCE(); __builtin_amdgcn_s_barrier(); FENCE(); } while (0)

// stage half 0 of tile kt -> buf sb: A rows 0..127 (2 ops) + B n-tiles 0..3 (1 op)
#define SP0(kt, sb) do { \
    stage16(Ab + (kt) * 64,          &As[sb][tid * 8]); \
    stage16(Ab + 65536 + (kt) * 64,  &As[sb][4096 + tid * 8]); \
    stage16(Bg0 + (kt) * 1024,       &Bs[sb][tid * 8]); \
} while (0)
// stage half 1: A rows 128..255 (2 ops) + B n-tiles 4..7 (1 op)
#define SP1(kt, sb) do { \
    stage16(Ab + 131072 + (kt) * 64, &As[sb][8192 + tid * 8]); \
    stage16(Ab + 196608 + (kt) * 64, &As[sb][12288 + tid * 8]); \
    stage16(Bg1 + (kt) * 1024,       &Bs[sb][4096 + tid * 8]); \
} while (0)

// 8 MFMA: A subtile i, both k-halves, all 4 B n-tiles
#define MM(i, ak0, ak1) do { \
    acc[i][0] = __builtin_amdgcn_mfma_f32_16x16x32_bf16(ak0, bb[0][0], acc[i][0], 0, 0, 0); \
    acc[i][1] = __builtin_amdgcn_mfma_f32_16x16x32_bf16(ak0, bb[1][0], acc[i][1], 0, 0, 0); \
    acc[i][2] = __builtin_amdgcn_mfma_f32_16x16x32_bf16(ak0, bb[2][0], acc[i][2], 0, 0, 0); \
    acc[i][3] = __builtin_amdgcn_mfma_f32_16x16x32_bf16(ak0, bb[3][0], acc[i][3], 0, 0, 0); \
    acc[i][0] = __builtin_amdgcn_mfma_f32_16x16x32_bf16(ak1, bb[0][1], acc[i][0], 0, 0, 0); \
    acc[i][1] = __builtin_amdgcn_mfma_f32_16x16x32_bf16(ak1, bb[1][1], acc[i][1], 0, 0, 0); \
    acc[i][2] = __builtin_amdgcn_mfma_f32_16x16x32_bf16(ak1, bb[2][1], acc[i][2], 0, 0, 0); \
    acc[i][3] = __builtin_amdgcn_mfma_f32_16x16x32_bf16(ak1, bb[3][1], acc[i][3], 0, 0, 0); \
} while (0)

#define LOADBB(ct) do { \
    const unsigned short* bp = &Bs[ct][bfrag]; \
    bb[0][0] = *(const short8*)&bp[0];    bb[0][1] = *(const short8*)&bp[512]; \
    bb[1][0] = *(const short8*)&bp[1024]; bb[1][1] = *(const short8*)&bp[1536]; \
    bb[2][0] = *(const short8*)&bp[2048]; bb[2][1] = *(const short8*)&bp[2560]; \
    bb[3][0] = *(const short8*)&bp[3072]; bb[3][1] = *(const short8*)&bp[3584]; \
} while (0)

__global__ __launch_bounds__(512, 2) void gemm_qkv_kernel(
    const unsigned short* __restrict__ encb, const unsigned short* __restrict__ decb,
    const unsigned short* __restrict__ kvwt, const unsigned short* __restrict__ qwt,
    const float* __restrict__ q_b, const float* __restrict__ k_b, const float* __restrict__ v_b,
    unsigned short* __restrict__ Qb, unsigned short* __restrict__ Kb,
    unsigned short* __restrict__ Vtb) {
    __shared__ __align__(16) unsigned short As[3][16384];  // 96 KB: A tiles 256x64, triple-buffered
    __shared__ __align__(16) unsigned short Bs[3][8192];   // 48 KB: B tiles 128x64 fragment-major
    const int id = blockIdx.x;
    const bool isKV = id < 512;
    const unsigned short *A, *Bw;
    int m0, n0;
    if (isKV) {
        const int x = id & 7, w = id >> 3;     // XCD-aware: id&7 -> m superpanel
        A = encb; Bw = kvwt;
        m0 = (x * 4 + (w >> 4)) * 256;         // 32 m-tiles of 256
        n0 = (w & 15) * 128;                   // 16 n-tiles of 128
    } else {
        const int i2 = id - 512, x = i2 & 7, w = i2 >> 3;
        A = decb; Bw = qwt;
        m0 = (x * 2 + (w >> 3)) * 256;         // 16 m-tiles
        n0 = (w & 7) * 128;                    // 8 n-tiles
    }
    const int tid = threadIdx.x;
    const int wave = tid >> 6, lane = tid & 63, quad = lane >> 4, l16 = lane & 15;
    const int wr = wave >> 1, wc = wave & 1;   // 4x2 wave grid, 64x64 per wave
    f32x4 acc[4][4] = {};

    // A staging: op i covers rows i*64..i*64+63; linear LDS dest (tid*16B);
    // inverse-swizzled global k source so swizzled ds_read is logical (verified: 0 conflicts).
    const int srow = tid >> 3;
    const int ksrc = ((tid ^ srow) & 7) * 8;
    const unsigned short* Ab = A + (size_t)(m0 + srow) * 1024 + ksrc;
    // B staging: fragment-major global -> linear LDS; op o covers n-tiles o*4..o*4+3 (1KB each/kt..).
    const unsigned short* Bg0 = Bw + (size_t)((n0 >> 4) + (tid >> 7)) * 16384 + (tid & 127) * 8;
    const unsigned short* Bg1 = Bg0 + (size_t)4 * 16384;

    // swizzled A read offsets (bytes): subtile i at rbase + i*2048 + ((kc*64+quad*16) ^ rswz)
    const int rbase = (wr * 64 + l16) * 128;
    const int rswz = (l16 & 7) << 4;
    const int rk0 = (quad * 16) ^ rswz;
    const int rk1 = (64 + quad * 16) ^ rswz;
    // B fragment read base (elements): + j*1024 + kc*512
    const int bfrag = wc * 4096 + quad * 128 + l16 * 8;

    // ---------------- prologue: tiles 0,1 fully staged; wait tile 0 only ----------------
    SP0(0, 0); SP1(0, 0);
    SP0(1, 1); SP1(1, 1);
    FENCE();
    asm volatile("s_waitcnt vmcnt(6)" ::: "memory");   // tile0's 6 ops done; tile1's may fly
    __builtin_amdgcn_s_barrier();
    FENCE();

    // ---------------- main loop: tiles 0..13, staging tile kt+2 ----------------
    int ct = 0, st = 2;
    for (int kt = 0; kt < 14; ++kt) {
        const char* ap = (const char*)&As[ct][0] + rbase;
        short8 bb[4][2];
        // ---- phase A: 12 ds_read (all B + A subtiles 0,1) || stage half0(kt+2) -> 16 MFMA ----
        LOADBB(ct);
        short8 a00 = *(const short8*)(ap + rk0);
        short8 a01 = *(const short8*)(ap + rk1);
        short8 a10 = *(const short8*)(ap + 2048 + rk0);
        short8 a11 = *(const short8*)(ap + 2048 + rk1);
        SP0(kt + 2, st);
        FENCE();
        __builtin_amdgcn_s_barrier();
        FENCE();
        __builtin_amdgcn_s_setprio(1);
        MM(0, a00, a01);
        MM(1, a10, a11);
        __builtin_amdgcn_s_setprio(0);
        BARRIER();
        // ---- phase B: 4 ds_read (A subtiles 2,3) || stage half1(kt+2) ; vmcnt(6) ; 16 MFMA ----
        short8 a20 = *(const short8*)(ap + 4096 + rk0);
        short8 a21 = *(const short8*)(ap + 4096 + rk1);
        short8 a30 = *(const short8*)(ap + 6144 + rk0);
        short8 a31 = *(const short8*)(ap + 6144 + rk1);
        SP1(kt + 2, st);
        FENCE();
        asm volatile("s_waitcnt vmcnt(6)" ::: "memory");  // drains stage(kt+1); stage(kt+2) in flight
        __builtin_amdgcn_s_barrier();
        FENCE();
        __builtin_amdgcn_s_setprio(1);
        MM(2, a20, a21);
        MM(3, a30, a31);
        __builtin_amdgcn_s_setprio(0);
        BARRIER();
        ct = (ct == 2) ? 0 : ct + 1;
        st = (st == 2) ? 0 : st + 1;
    }
    // ---- tile 14 (buf 2): no staging; drain remaining stage(15) with vmcnt(0) ----
    {
        const char* ap = (const char*)&As[2][0] + rbase;
        short8 bb[4][2];
        LOADBB(2);
        short8 a00 = *(const short8*)(ap + rk0);
        short8 a01 = *(const short8*)(ap + rk1);
        short8 a10 = *(const short8*)(ap + 2048 + rk0);
        short8 a11 = *(const short8*)(ap + 2048 + rk1);
        __builtin_amdgcn_s_setprio(1);
        MM(0, a00, a01);
        MM(1, a10, a11);
        __builtin_amdgcn_s_setprio(0);
        short8 a20 = *(const short8*)(ap + 4096 + rk0);
        short8 a21 = *(const short8*)(ap + 4096 + rk1);
        short8 a30 = *(const short8*)(ap + 6144 + rk0);
        short8 a31 = *(const short8*)(ap + 6144 + rk1);
        __builtin_amdgcn_s_setprio(1);
        MM(2, a20, a21);
        MM(3, a30, a31);
        __builtin_amdgcn_s_setprio(0);
        FENCE();
        asm volatile("s_waitcnt vmcnt(0)" ::: "memory");  // stage(15) done (epilogue drain)
        __builtin_amdgcn_s_barrier();
        FENCE();
    }
    // ---- tile 15 (buf 0): pure compute ----
    {
        const char* ap = (const char*)&As[0][0] + rbase;
        short8 bb[4][2];
        LOADBB(0);
        short8 a00 = *(const short8*)(ap + rk0);
        short8 a01 = *(const short8*)(ap + rk1);
        short8 a10 = *(const short8*)(ap + 2048 + rk0);
        short8 a11 = *(const short8*)(ap + 2048 + rk1);
        short8 a20 = *(const short8*)(ap + 4096 + rk0);
        short8 a21 = *(const short8*)(ap + 4096 + rk1);
        short8 a30 = *(const short8*)(ap + 6144 + rk0);
        short8 a31 = *(const short8*)(ap + 6144 + rk1);
        __builtin_amdgcn_s_setprio(1);
        MM(0, a00, a01);
        MM(1, a10, a11);
        MM(2, a20, a21);
        MM(3, a30, a31);
        __builtin_amdgcn_s_setprio(0);
    }

    // ---------------- epilogue (layouts unchanged) ----------------
    #pragma unroll
    for (int i = 0; i < 4; ++i) {
        #pragma unroll
        for (int j = 0; j < 4; ++j) {
            const int gc = n0 + wc * 64 + j * 16 + l16;
            const int gr0 = m0 + wr * 64 + i * 16 + quad * 4;
            if (!isKV) {
                const float bv = q_b[gc];
                const int h = gc >> 6, d = gc & 63;
                #pragma unroll
                for (int rr = 0; rr < 4; ++rr) {
                    int gr = gr0 + rr, b = gr >> 10, sq = gr & 1023;
                    float v = (acc[i][j][rr] + bv) * 0.18033688011112042f;  // 1/(8 ln2)
                    Qb[(((size_t)(b * NH + h) * SDEC + sq) << 6) + d] = f2bf(v);
                }
            } else if (gc < 1024) {
                // K fragment-major per bh: [sk/16][d/8][sk%16][d%8]
                const float bv = k_b[gc];
                const int h = gc >> 6, d = gc & 63;
                #pragma unroll
                for (int rr = 0; rr < 4; ++rr) {
                    int gr = gr0 + rr, b = gr >> 11, sk = gr & 2047;
                    size_t off = (size_t)(b * NH + h) * 131072 + (size_t)(sk >> 4) * 1024
                               + ((d >> 3) << 7) + ((sk & 15) << 3) + (d & 7);
                    Kb[off] = f2bf(acc[i][j][rr] + bv);
                }
            } else {
                // V^T fragment-major per bh: [d/16][key/8][d%16][key%8]; 4 consecutive keys -> 8B store
                const int gc2 = gc & 1023;
                const float bv = v_b[gc2];
                const int h = gc2 >> 6, d = gc2 & 63;
                const int b = gr0 >> 11, sk0 = gr0 & 2047;
                size_t off = (size_t)(b * NH + h) * 131072 + (size_t)(d >> 4) * 32768
                           + (size_t)(sk0 >> 3) * 128 + ((d & 15) << 3) + (sk0 & 7);
                uint2 pk;
                pk.x = pk2bf(acc[i][j][0] + bv, acc[i][j][1] + bv);
                pk.y = pk2bf(acc[i][j][2] + bv, acc[i][j][3] + bv);
                *(uint2*)&Vtb[off] = pk;
            }
        }
    }
}

// ---------------- output projection GEMM: out[4096,1024] fp32; B direct, XCD swizzle ----------------
__global__ __launch_bounds__(256) void gemm_o_kernel(const unsigned short* __restrict__ A,
                                                     const unsigned short* __restrict__ Bw,
                                                     const float* __restrict__ bias,
                                                     float* __restrict__ Cout) {
    __shared__ __align__(16) unsigned short As[2][64 * 32];
    const int id = blockIdx.x, x = id & 7, w = id >> 3;
    const int m0 = (x * 8 + (w >> 3)) * 64, n0 = (w & 7) * 128;
    const int tid = threadIdx.x;
    const int wave = tid >> 6, lane = tid & 63, quad = lane >> 4, l16 = lane & 15;
    const int r16 = lane >> 2, c8 = (lane & 3) * 8;
    f32x4 acc[4][2] = {};
    const unsigned short* Bbase = Bw + (size_t)((n0 >> 4) + wave * 2) * 16384 + quad * 128 + l16 * 8;
    short8 bcur[2], bnxt[2];
    #pragma unroll
    for (int j = 0; j < 2; ++j) bcur[j] = *(const short8*)&Bbase[j * 16384];
    {
        const int rowA = wave * 16 + r16;
        stage16(&A[(size_t)(m0 + rowA) * DM + c8], &As[0][rowA * 32 + c8]);
    }
    for (int it = 0; it < 32; ++it) {
        const int bf = it & 1;
        __syncthreads();
        if (it < 31) {
            const int kb2 = (it + 1) * 32, nb = bf ^ 1;
            const int rowA = wave * 16 + r16;
            stage16(&A[(size_t)(m0 + rowA) * DM + kb2 + c8], &As[nb][rowA * 32 + c8]);
            #pragma unroll
            for (int j = 0; j < 2; ++j) bnxt[j] = *(const short8*)&Bbase[j * 16384 + kb2 * 16];
        }
        short8 af[4];
        #pragma unroll
        for (int i = 0; i < 4; ++i) af[i] = *(const short8*)&As[bf][(i * 16 + l16) * 32 + quad * 8];
        #pragma unroll
        for (int i = 0; i < 4; ++i)
            #pragma unroll
            for (int j = 0; j < 2; ++j)
                acc[i][j] = __builtin_amdgcn_mfma_f32_16x16x32_bf16(af[i], bcur[j], acc[i][j], 0, 0, 0);
        #pragma unroll
        for (int j = 0; j < 2; ++j) bcur[j] = bnxt[j];
    }
    #pragma unroll
    for (int i = 0; i < 4; ++i)
        #pragma unroll
        for (int j = 0; j < 2; ++j) {
            const int gc = n0 + wave * 32 + j * 16 + l16;
            const float bv = bias[gc];
            #pragma unroll
            for (int rr = 0; rr < 4; ++rr) {
                const int gr = m0 + i * 16 + quad * 4 + rr;
                Cout[(size_t)gr * DM + gc] = acc[i][j][rr] + bv;
            }
        }
}

// ---------------- flash cross-attention: barrier-free, direct fragment loads ----------------
__global__ __launch_bounds__(256) void attn_kernel(const unsigned short* __restrict__ Qb,
                                                   const unsigned short* __restrict__ Kb,
                                                   const unsigned short* __restrict__ Vtb,
                                                   const int* __restrict__ mask,
                                                   unsigned short* __restrict__ Xb) {
    __shared__ __align__(16) unsigned short Ps[4][16 * 72];
    const int id = blockIdx.x, x = id & 7, r = id >> 3;
    const int bh = x * 8 + (r & 7), qt = r >> 3;
    const int b = bh >> 4, h = bh & 15;
    const int q0 = qt * 128;
    const int tid = threadIdx.x, wave = tid >> 6, lane = tid & 63;
    const int quad = lane >> 4, l16 = lane & 15;
    const int lo = quad * 128 + l16 * 8;  // shared lane offset for kA/vB fragment loads

    const unsigned short* Kfp = Kb + (size_t)bh * 131072;
    const unsigned short* Vfp = Vtb + (size_t)bh * 131072;
    const int* mp = mask + (size_t)b * SENC;

    short8 qf[2][2];  // B-operand: query n = l16 within group g
    {
        const unsigned short* Qp = Qb + ((size_t)bh * SDEC + q0 + wave * 32) * HD;
        #pragma unroll
        for (int g = 0; g < 2; ++g) {
            qf[g][0] = *(const short8*)&Qp[(g * 16 + l16) * HD + quad * 8];
            qf[g][1] = *(const short8*)&Qp[(g * 16 + l16) * HD + 32 + quad * 8];
        }
    }

    float lsum[2] = {0.f, 0.f};
    f32x4 o[2][4] = {};

    for (int kb = 0; kb < SENC; kb += 64) {
        short8 kA0[4], kA1[4], vB0[4], vB1[4];
        const unsigned short* kt = Kfp + (size_t)(kb >> 4) * 1024 + lo;
        const unsigned short* vt = Vfp + (size_t)(kb >> 3) * 128 + lo;
        #pragma unroll
        for (int j = 0; j < 4; ++j) {
            kA0[j] = *(const short8*)&kt[j * 1024];
            kA1[j] = *(const short8*)&kt[j * 1024 + 512];
            vB0[j] = *(const short8*)&vt[j * 32768];
            vB1[j] = *(const short8*)&vt[j * 32768 + 512];
        }
        int4 mi[4];
        #pragma unroll
        for (int j = 0; j < 4; ++j) mi[j] = *(const int4*)&mp[kb + j * 16 + quad * 4];
        #pragma unroll
        for (int g = 0; g < 2; ++g) {
            f32x4 st[4];
            #pragma unroll
            for (int j = 0; j < 4; ++j) {
                f32x4 z = {0.f, 0.f, 0.f, 0.f};
                z = __builtin_amdgcn_mfma_f32_16x16x32_bf16(kA0[j], qf[g][0], z, 0, 0, 0);
                st[j] = __builtin_amdgcn_mfma_f32_16x16x32_bf16(kA1[j], qf[g][1], z, 0, 0, 0);
            }
            #pragma unroll
            for (int j = 0; j < 4; ++j) {
                float p0 = mi[j].x ? 0.f : fexp2(st[j][0]);
                float p1 = mi[j].y ? 0.f : fexp2(st[j][1]);
                float p2 = mi[j].z ? 0.f : fexp2(st[j][2]);
                float p3 = mi[j].w ? 0.f : fexp2(st[j][3]);
                lsum[g] += (p0 + p1) + (p2 + p3);
                uint2 pkv;
                pkv.x = pk2bf(p0, p1);
                pkv.y = pk2bf(p2, p3);
                *(uint2*)&Ps[wave][l16 * 72 + j * 16 + quad * 4] = pkv;
            }
            asm volatile("s_waitcnt lgkmcnt(0)" ::: "memory");  // Ps write->read, same wave
            short8 pA0 = *(const short8*)&Ps[wave][l16 * 72 + quad * 8];
            short8 pA1 = *(const short8*)&Ps[wave][l16 * 72 + 32 + quad * 8];
            #pragma unroll
            for (int dj = 0; dj < 4; ++dj) {
                o[g][dj] = __builtin_amdgcn_mfma_f32_16x16x32_bf16(pA0, vB0[dj], o[g][dj], 0, 0, 0);
                o[g][dj] = __builtin_amdgcn_mfma_f32_16x16x32_bf16(pA1, vB1[dj], o[g][dj], 0, 0, 0);
            }
        }
    }
    #pragma unroll
    for (int g = 0; g < 2; ++g) {
        float lg = lsum[g];
        lg += __shfl_xor(lg, 16);
        lg += __shfl_xor(lg, 32);
        #pragma unroll
        for (int rr = 0; rr < 4; ++rr) {
            float iv = 1.0f / __shfl(lg, quad * 4 + rr, 64);
            int sq = q0 + wave * 32 + g * 16 + quad * 4 + rr;
            #pragma unroll
            for (int dj = 0; dj < 4; ++dj)
                Xb[((size_t)(b * SDEC) + sq) * DM + h * HD + dj * 16 + l16] = f2bf(o[g][dj][rr] * iv);
        }
    }
}

extern "C" void kernel_launch(void* const* d_in, const int* in_sizes, int n_in,
                              void* d_out, int out_size, void* d_ws, size_t ws_size,
                              hipStream_t stream) {
    const float* enc   = (const float*)d_in[0];
    const int*   emask = (const int*)d_in[1];
    const float* dec   = (const float*)d_in[2];
    const float* q_w   = (const float*)d_in[3];
    const float* q_b   = (const float*)d_in[4];
    const float* k_w   = (const float*)d_in[5];
    const float* k_b   = (const float*)d_in[6];
    const float* v_w   = (const float*)d_in[7];
    const float* v_b   = (const float*)d_in[8];
    const float* o_w   = (const float*)d_in[9];
    const float* o_b   = (const float*)d_in[10];
    float* out = (float*)d_out;

    char* ws = (char*)d_ws;
    unsigned short* decb = (unsigned short*)ws; ws += (size_t)4096 * 1024 * 2;  // dec||enc contiguous
    unsigned short* encb = (unsigned short*)ws; ws += (size_t)8192 * 1024 * 2;
    unsigned short* qwt  = (unsigned short*)ws; ws += (size_t)1024 * 1024 * 2;
    unsigned short* kvwt = (unsigned short*)ws; ws += (size_t)2048 * 1024 * 2;
    unsigned short* owt  = (unsigned short*)ws; ws += (size_t)1024 * 1024 * 2;
    unsigned short* Qb   = (unsigned short*)ws; ws += (size_t)BB * NH * SDEC * HD * 2;
    unsigned short* Kb   = (unsigned short*)ws; ws += (size_t)BB * NH * SENC * HD * 2;
    unsigned short* Vtb  = (unsigned short*)ws; ws += (size_t)BB * NH * HD * SENC * 2;
    unsigned short* Xb   = (unsigned short*)ws; ws += (size_t)4096 * 1024 * 2;

    prep_kernel<<<13312, 256, 0, stream>>>(dec, enc, decb, q_w, k_w, v_w, o_w, qwt, kvwt, owt);
    gemm_qkv_kernel<<<640, 512, 0, stream>>>(encb, decb, kvwt, qwt, q_b, k_b, v_b, Qb, Kb, Vtb);
    attn_kernel<<<512, 256, 0, stream>>>(Qb, Kb, Vtb, emask, Xb);
    gemm_o_kernel<<<512, 256, 0, stream>>>(Xb, owt, o_b, out);
}

// Round 4
// 254.113 us; speedup vs baseline: 1.0715x; 1.0291x over previous
//
#include <hip/hip_runtime.h>
#include <hip/hip_bf16.h>
#include <cstdint>

#define BB   4
#define SENC 2048
#define SDEC 1024
#define DM   1024
#define NH   16
#define HD   64

using short8 = __attribute__((ext_vector_type(8))) short;
using f32x4  = __attribute__((ext_vector_type(4))) float;

// round-half-up fp32 -> bf16 (2 VALU ops)
__device__ inline unsigned short f2bf(float f) {
    return (unsigned short)((__builtin_bit_cast(unsigned int, f) + 0x8000u) >> 16);
}
// pack two fp32 -> bf16x2 dword
__device__ inline unsigned int pk2bf(float a, float b) {
    return ((__builtin_bit_cast(unsigned int, a) + 0x8000u) >> 16) |
           ((__builtin_bit_cast(unsigned int, b) + 0x8000u) & 0xffff0000u);
}

__device__ inline float fexp2(float x) {
#if __has_builtin(__builtin_amdgcn_exp2f)
    return __builtin_amdgcn_exp2f(x);
#else
    return exp2f(x);
#endif
}

#if __has_builtin(__builtin_amdgcn_global_load_lds)
#define HAS_GLL 1
#endif

__device__ inline void stage16(const void* g, void* l) {
#ifdef HAS_GLL
    typedef __attribute__((address_space(1))) const unsigned int guint;
    typedef __attribute__((address_space(3))) unsigned int luint;
    __builtin_amdgcn_global_load_lds((guint*)g, (luint*)l, 16, 0, 0);
#else
    *(short8*)l = *(const short8*)g;
#endif
}

// ---------------- fused prep: activation convert + weight transpose to fragment-major ----------------
// blocks [0,12288): fp32->bf16 convert of dec (4M) then enc (8M) into contiguous actb
// blocks [12288,13312): W[K,N] fp32 -> W'[n/16][k/8][n%16][k%8] bf16 (MFMA-B-fragment-major)
// transpose writes vectorized: each thread packs 8 consecutive k into one 16B store.
__global__ __launch_bounds__(256) void prep_kernel(
    const float* __restrict__ dec, const float* __restrict__ enc,
    unsigned short* __restrict__ actb,
    const float* __restrict__ qw, const float* __restrict__ kw,
    const float* __restrict__ vw, const float* __restrict__ ow,
    unsigned short* __restrict__ qwt, unsigned short* __restrict__ kvwt,
    unsigned short* __restrict__ owt) {
    __shared__ float t[64][65];
    const int id = blockIdx.x, tid = threadIdx.x;
    if (id < 12288) {
        const int nd = BB * SDEC * DM;  // 4M
        int i = (id * 256 + tid) * 4;
        const float* src = (i < nd) ? (dec + i) : (enc + (i - nd));
        float4 v = *(const float4*)src;
        ushort4 o;
        o.x = f2bf(v.x); o.y = f2bf(v.y); o.z = f2bf(v.z); o.w = f2bf(v.w);
        *(ushort4*)(actb + i) = o;
        return;
    }
    const int id2 = id - 12288;
    const int z = id2 >> 8, ky = (id2 >> 4) & 15, nx = id2 & 15;
    const float* src; unsigned short* dst;
    switch (z) {
        case 0:  src = qw; dst = qwt; break;
        case 1:  src = kw; dst = kvwt; break;
        case 2:  src = vw; dst = kvwt + (size_t)64 * 16384; break;  // second 1024 n-rows
        default: src = ow; dst = owt; break;
    }
    const int k0 = ky * 64, n0 = nx * 64;
    #pragma unroll
    for (int it = 0; it < 16; ++it) {
        int e = it * 256 + tid, r = e >> 6, c = e & 63;  // r = local k, c = local n
        t[r][c] = src[(size_t)(k0 + r) * DM + n0 + c];
    }
    __syncthreads();
    // packed transpose writes: kg = k-octet (wave-uniform), r = local n (lane-linear)
    #pragma unroll
    for (int it = 0; it < 2; ++it) {
        int e = it * 256 + tid;
        int kg = e >> 6, r = e & 63;
        short8 w;
        #pragma unroll
        for (int j = 0; j < 8; ++j) w[j] = (short)f2bf(t[kg * 8 + j][r]);
        size_t off = (size_t)((n0 + r) >> 4) * 16384 + (size_t)((k0 >> 3) + kg) * 128
                   + ((r & 15) << 3);
        *(short8*)(dst + off) = w;
    }
}

// ---------------- fused Q/K/V projection GEMM (round-0 structure + conflict-free LDS swizzle) -------
// A via LDS (rotation dbuf, global_load_lds); B (weights) DIRECT from global fragment-major,
// register-rotated one iter ahead. 1280 blocks x 256 threads -> high cross-block TLP (the
// measured winner on this small-K GEMM; deep 1-block/CU pipelines regressed, rounds 2-3).
// T2 swizzle: 16B col-slot ^= (row>>1)&3 -> the former 8-way ds_read_b128 conflict becomes
// 2-way (free). Linear LDS dest + inverse-swizzled GLOBAL source + swizzled read (rule #21).
// blocks [0,1024):  encb[8192,1024] @ kvW'^T -> K (frag-major per bh) / V^T (frag-major per bh)
// blocks [1024,1280): decb[4096,1024] @ qW'^T -> Q ([b,h,sq,d] row-major, scaled)
__global__ __launch_bounds__(256) void gemm_qkv_kernel(
    const unsigned short* __restrict__ encb, const unsigned short* __restrict__ decb,
    const unsigned short* __restrict__ kvwt, const unsigned short* __restrict__ qwt,
    const float* __restrict__ q_b, const float* __restrict__ k_b, const float* __restrict__ v_b,
    unsigned short* __restrict__ Qb, unsigned short* __restrict__ Kb,
    unsigned short* __restrict__ Vtb) {
    __shared__ __align__(16) unsigned short As[2][128 * 32];
    const int id = blockIdx.x;
    const bool isKV = id < 1024;
    const unsigned short *A, *Bw;
    int m0, n0;
    if (isKV) {
        const int x = id & 7, w = id >> 3;
        A = encb; Bw = kvwt;
        m0 = (x * 8 + (w >> 4)) * 128;
        n0 = (w & 15) * 128;
    } else {
        const int i2 = id - 1024, x = i2 & 7, w = i2 >> 3;
        A = decb; Bw = qwt;
        m0 = (x * 4 + (w >> 3)) * 128;
        n0 = (w & 7) * 128;
    }
    const int tid = threadIdx.x;
    const int wave = tid >> 6, lane = tid & 63, quad = lane >> 4, l16 = lane & 15;
    const int wr = wave >> 1, wc = wave & 1;
    const int r16 = lane >> 2, c8 = (lane & 3) * 8;
    // inverse-swizzled global k source slot (stage) and swizzled LDS read slot:
    const int c8s = (((lane & 3) ^ ((r16 >> 1) & 3)) * 8);
    const int qsw8 = (quad ^ ((l16 >> 1) & 3)) * 8;
    f32x4 acc[4][4] = {};

    // B fragment base: tile (n0/16 + wc*4 + j), k-chunk (kb/8 + quad), row l16
    const unsigned short* Bbase = Bw + (size_t)(n0 >> 4) * 16384 + (size_t)(wc * 4) * 16384
                                + quad * 128 + l16 * 8;
    short8 bcur[4], bnxt[4];
    #pragma unroll
    for (int j = 0; j < 4; ++j) bcur[j] = *(const short8*)&Bbase[j * 16384];  // kb = 0

    // prologue: stage A k-block 0 into buf 0
    #pragma unroll
    for (int i = 0; i < 2; ++i) {
        const int row = wave * 32 + i * 16 + r16;
        stage16(&A[(size_t)(m0 + row) * DM + c8s], &As[0][row * 32 + c8]);
    }
    for (int it = 0; it < 32; ++it) {
        const int bf = it & 1;
        __syncthreads();  // drains vmcnt: A-stage of buf[bf] AND last iter's bnxt loads
        if (it < 31) {
            const int kb2 = (it + 1) * 32, nb = bf ^ 1;
            #pragma unroll
            for (int i = 0; i < 2; ++i) {
                const int row = wave * 32 + i * 16 + r16;
                stage16(&A[(size_t)(m0 + row) * DM + kb2 + c8s], &As[nb][row * 32 + c8]);
            }
            #pragma unroll
            for (int j = 0; j < 4; ++j)
                bnxt[j] = *(const short8*)&Bbase[j * 16384 + kb2 * 16];  // (kb2/8)*128
        }
        short8 af[4];
        #pragma unroll
        for (int i = 0; i < 4; ++i) af[i] = *(const short8*)&As[bf][(wr * 64 + i * 16 + l16) * 32 + qsw8];
        #pragma unroll
        for (int i = 0; i < 4; ++i)
            #pragma unroll
            for (int j = 0; j < 4; ++j)
                acc[i][j] = __builtin_amdgcn_mfma_f32_16x16x32_bf16(af[i], bcur[j], acc[i][j], 0, 0, 0);
        #pragma unroll
        for (int j = 0; j < 4; ++j) bcur[j] = bnxt[j];
    }
    #pragma unroll
    for (int i = 0; i < 4; ++i) {
        #pragma unroll
        for (int j = 0; j < 4; ++j) {
            const int gc = n0 + wc * 64 + j * 16 + l16;
            const int gr0 = m0 + wr * 64 + i * 16 + quad * 4;
            if (!isKV) {
                const float bv = q_b[gc];
                const int h = gc >> 6, d = gc & 63;
                #pragma unroll
                for (int rr = 0; rr < 4; ++rr) {
                    int gr = gr0 + rr, b = gr >> 10, sq = gr & 1023;
                    float v = (acc[i][j][rr] + bv) * 0.18033688011112042f;  // 1/(8 ln2)
                    Qb[(((size_t)(b * NH + h) * SDEC + sq) << 6) + d] = f2bf(v);
                }
            } else if (gc < 1024) {
                // K fragment-major per bh: [sk/16][d/8][sk%16][d%8]
                const float bv = k_b[gc];
                const int h = gc >> 6, d = gc & 63;
                #pragma unroll
                for (int rr = 0; rr < 4; ++rr) {
                    int gr = gr0 + rr, b = gr >> 11, sk = gr & 2047;
                    size_t off = (size_t)(b * NH + h) * 131072 + (size_t)(sk >> 4) * 1024
                               + ((d >> 3) << 7) + ((sk & 15) << 3) + (d & 7);
                    Kb[off] = f2bf(acc[i][j][rr] + bv);
                }
            } else {
                // V^T fragment-major per bh: [d/16][key/8][d%16][key%8]; 4 consecutive keys -> 8B store
                const int gc2 = gc & 1023;
                const float bv = v_b[gc2];
                const int h = gc2 >> 6, d = gc2 & 63;
                const int b = gr0 >> 11, sk0 = gr0 & 2047;
                size_t off = (size_t)(b * NH + h) * 131072 + (size_t)(d >> 4) * 32768
                           + (size_t)(sk0 >> 3) * 128 + ((d & 15) << 3) + (sk0 & 7);
                uint2 pk;
                pk.x = pk2bf(acc[i][j][0] + bv, acc[i][j][1] + bv);
                pk.y = pk2bf(acc[i][j][2] + bv, acc[i][j][3] + bv);
                *(uint2*)&Vtb[off] = pk;
            }
        }
    }
}

// ---------------- output projection GEMM: out[4096,1024] fp32; B direct, XCD swizzle ----------------
// same LDS swizzle as gemm_qkv (identical tile pattern had the same 8-way conflict)
__global__ __launch_bounds__(256) void gemm_o_kernel(const unsigned short* __restrict__ A,
                                                     const unsigned short* __restrict__ Bw,
                                                     const float* __restrict__ bias,
                                                     float* __restrict__ Cout) {
    __shared__ __align__(16) unsigned short As[2][64 * 32];
    const int id = blockIdx.x, x = id & 7, w = id >> 3;
    const int m0 = (x * 8 + (w >> 3)) * 64, n0 = (w & 7) * 128;
    const int tid = threadIdx.x;
    const int wave = tid >> 6, lane = tid & 63, quad = lane >> 4, l16 = lane & 15;
    const int r16 = lane >> 2, c8 = (lane & 3) * 8;
    const int c8s = (((lane & 3) ^ ((r16 >> 1) & 3)) * 8);
    const int qsw8 = (quad ^ ((l16 >> 1) & 3)) * 8;
    f32x4 acc[4][2] = {};
    const unsigned short* Bbase = Bw + (size_t)((n0 >> 4) + wave * 2) * 16384 + quad * 128 + l16 * 8;
    short8 bcur[2], bnxt[2];
    #pragma unroll
    for (int j = 0; j < 2; ++j) bcur[j] = *(const short8*)&Bbase[j * 16384];
    {
        const int rowA = wave * 16 + r16;
        stage16(&A[(size_t)(m0 + rowA) * DM + c8s], &As[0][rowA * 32 + c8]);
    }
    for (int it = 0; it < 32; ++it) {
        const int bf = it & 1;
        __syncthreads();
        if (it < 31) {
            const int kb2 = (it + 1) * 32, nb = bf ^ 1;
            const int rowA = wave * 16 + r16;
            stage16(&A[(size_t)(m0 + rowA) * DM + kb2 + c8s], &As[nb][rowA * 32 + c8]);
            #pragma unroll
            for (int j = 0; j < 2; ++j) bnxt[j] = *(const short8*)&Bbase[j * 16384 + kb2 * 16];
        }
        short8 af[4];
        #pragma unroll
        for (int i = 0; i < 4; ++i) af[i] = *(const short8*)&As[bf][(i * 16 + l16) * 32 + qsw8];
        #pragma unroll
        for (int i = 0; i < 4; ++i)
            #pragma unroll
            for (int j = 0; j < 2; ++j)
                acc[i][j] = __builtin_amdgcn_mfma_f32_16x16x32_bf16(af[i], bcur[j], acc[i][j], 0, 0, 0);
        #pragma unroll
        for (int j = 0; j < 2; ++j) bcur[j] = bnxt[j];
    }
    #pragma unroll
    for (int i = 0; i < 4; ++i)
        #pragma unroll
        for (int j = 0; j < 2; ++j) {
            const int gc = n0 + wave * 32 + j * 16 + l16;
            const float bv = bias[gc];
            #pragma unroll
            for (int rr = 0; rr < 4; ++rr) {
                const int gr = m0 + i * 16 + quad * 4 + rr;
                Cout[(size_t)gr * DM + gc] = acc[i][j][rr] + bv;
            }
        }
}

// ---------------- flash cross-attention: barrier-free, direct fragment loads, K-prefetch ----------
// K/V stored fragment-major per bh -> kA/vB fragments load as contiguous 1KB global bursts
// (identical addresses across the 4 waves -> L1 broadcast). Only P round-trips through LDS
// (per-wave buffer). No __syncthreads anywhere. NEW: K fragments for iteration kb+64 are
// prefetched one iteration ahead (register rotation) -> their global latency hides under the
// current iteration's QK+softmax+PV; V/mask latency already hides under QK+softmax.
__global__ __launch_bounds__(256) void attn_kernel(const unsigned short* __restrict__ Qb,
                                                   const unsigned short* __restrict__ Kb,
                                                   const unsigned short* __restrict__ Vtb,
                                                   const int* __restrict__ mask,
                                                   unsigned short* __restrict__ Xb) {
    __shared__ __align__(16) unsigned short Ps[4][16 * 72];
    const int id = blockIdx.x, x = id & 7, r = id >> 3;
    const int bh = x * 8 + (r & 7), qt = r >> 3;
    const int b = bh >> 4, h = bh & 15;
    const int q0 = qt * 128;
    const int tid = threadIdx.x, wave = tid >> 6, lane = tid & 63;
    const int quad = lane >> 4, l16 = lane & 15;
    const int lo = quad * 128 + l16 * 8;  // shared lane offset for kA/vB fragment loads

    const unsigned short* Kfp = Kb + (size_t)bh * 131072;
    const unsigned short* Vfp = Vtb + (size_t)bh * 131072;
    const int* mp = mask + (size_t)b * SENC;

    short8 qf[2][2];  // B-operand: query n = l16 within group g
    {
        const unsigned short* Qp = Qb + ((size_t)bh * SDEC + q0 + wave * 32) * HD;
        #pragma unroll
        for (int g = 0; g < 2; ++g) {
            qf[g][0] = *(const short8*)&Qp[(g * 16 + l16) * HD + quad * 8];
            qf[g][1] = *(const short8*)&Qp[(g * 16 + l16) * HD + 32 + quad * 8];
        }
    }

    float lsum[2] = {0.f, 0.f};
    f32x4 o[2][4] = {};

    // prime K fragments for kb = 0
    short8 kA0c[4], kA1c[4];
    {
        const unsigned short* kt0 = Kfp + lo;
        #pragma unroll
        for (int j = 0; j < 4; ++j) {
            kA0c[j] = *(const short8*)&kt0[j * 1024];
            kA1c[j] = *(const short8*)&kt0[j * 1024 + 512];
        }
    }

    for (int kb = 0; kb < SENC; kb += 64) {
        short8 vB0[4], vB1[4];
        const unsigned short* vt = Vfp + (size_t)(kb >> 3) * 128 + lo;
        #pragma unroll
        for (int j = 0; j < 4; ++j) {
            vB0[j] = *(const short8*)&vt[j * 32768];
            vB1[j] = *(const short8*)&vt[j * 32768 + 512];
        }
        // issue next iteration's K loads (latency hides under this iteration's compute)
        short8 kA0n[4], kA1n[4];
        const bool hasn = (kb + 64) < SENC;
        if (hasn) {
            const unsigned short* ktn = Kfp + (size_t)((kb + 64) >> 4) * 1024 + lo;
            #pragma unroll
            for (int j = 0; j < 4; ++j) {
                kA0n[j] = *(const short8*)&ktn[j * 1024];
                kA1n[j] = *(const short8*)&ktn[j * 1024 + 512];
            }
        }
        int4 mi[4];
        #pragma unroll
        for (int j = 0; j < 4; ++j) mi[j] = *(const int4*)&mp[kb + j * 16 + quad * 4];
        #pragma unroll
        for (int g = 0; g < 2; ++g) {
            f32x4 st[4];
            #pragma unroll
            for (int j = 0; j < 4; ++j) {
                f32x4 z = {0.f, 0.f, 0.f, 0.f};
                z = __builtin_amdgcn_mfma_f32_16x16x32_bf16(kA0c[j], qf[g][0], z, 0, 0, 0);
                st[j] = __builtin_amdgcn_mfma_f32_16x16x32_bf16(kA1c[j], qf[g][1], z, 0, 0, 0);
            }
            #pragma unroll
            for (int j = 0; j < 4; ++j) {
                float p0 = mi[j].x ? 0.f : fexp2(st[j][0]);
                float p1 = mi[j].y ? 0.f : fexp2(st[j][1]);
                float p2 = mi[j].z ? 0.f : fexp2(st[j][2]);
                float p3 = mi[j].w ? 0.f : fexp2(st[j][3]);
                lsum[g] += (p0 + p1) + (p2 + p3);
                uint2 pkv;
                pkv.x = pk2bf(p0, p1);
                pkv.y = pk2bf(p2, p3);
                *(uint2*)&Ps[wave][l16 * 72 + j * 16 + quad * 4] = pkv;
            }
            asm volatile("s_waitcnt lgkmcnt(0)" ::: "memory");  // Ps write->read, same wave
            short8 pA0 = *(const short8*)&Ps[wave][l16 * 72 + quad * 8];
            short8 pA1 = *(const short8*)&Ps[wave][l16 * 72 + 32 + quad * 8];
            #pragma unroll
            for (int dj = 0; dj < 4; ++dj) {
                o[g][dj] = __builtin_amdgcn_mfma_f32_16x16x32_bf16(pA0, vB0[dj], o[g][dj], 0, 0, 0);
                o[g][dj] = __builtin_amdgcn_mfma_f32_16x16x32_bf16(pA1, vB1[dj], o[g][dj], 0, 0, 0);
            }
        }
        if (hasn) {
            #pragma unroll
            for (int j = 0; j < 4; ++j) { kA0c[j] = kA0n[j]; kA1c[j] = kA1n[j]; }
        }
    }
    #pragma unroll
    for (int g = 0; g < 2; ++g) {
        float lg = lsum[g];
        lg += __shfl_xor(lg, 16);
        lg += __shfl_xor(lg, 32);
        #pragma unroll
        for (int rr = 0; rr < 4; ++rr) {
            float iv = 1.0f / __shfl(lg, quad * 4 + rr, 64);
            int sq = q0 + wave * 32 + g * 16 + quad * 4 + rr;
            #pragma unroll
            for (int dj = 0; dj < 4; ++dj)
                Xb[((size_t)(b * SDEC) + sq) * DM + h * HD + dj * 16 + l16] = f2bf(o[g][dj][rr] * iv);
        }
    }
}

extern "C" void kernel_launch(void* const* d_in, const int* in_sizes, int n_in,
                              void* d_out, int out_size, void* d_ws, size_t ws_size,
                              hipStream_t stream) {
    const float* enc   = (const float*)d_in[0];
    const int*   emask = (const int*)d_in[1];
    const float* dec   = (const float*)d_in[2];
    const float* q_w   = (const float*)d_in[3];
    const float* q_b   = (const float*)d_in[4];
    const float* k_w   = (const float*)d_in[5];
    const float* k_b   = (const float*)d_in[6];
    const float* v_w   = (const float*)d_in[7];
    const float* v_b   = (const float*)d_in[8];
    const float* o_w   = (const float*)d_in[9];
    const float* o_b   = (const float*)d_in[10];
    float* out = (float*)d_out;

    char* ws = (char*)d_ws;
    unsigned short* decb = (unsigned short*)ws; ws += (size_t)4096 * 1024 * 2;  // dec||enc contiguous
    unsigned short* encb = (unsigned short*)ws; ws += (size_t)8192 * 1024 * 2;
    unsigned short* qwt  = (unsigned short*)ws; ws += (size_t)1024 * 1024 * 2;
    unsigned short* kvwt = (unsigned short*)ws; ws += (size_t)2048 * 1024 * 2;
    unsigned short* owt  = (unsigned short*)ws; ws += (size_t)1024 * 1024 * 2;
    unsigned short* Qb   = (unsigned short*)ws; ws += (size_t)BB * NH * SDEC * HD * 2;
    unsigned short* Kb   = (unsigned short*)ws; ws += (size_t)BB * NH * SENC * HD * 2;
    unsigned short* Vtb  = (unsigned short*)ws; ws += (size_t)BB * NH * HD * SENC * 2;
    unsigned short* Xb   = (unsigned short*)ws; ws += (size_t)4096 * 1024 * 2;

    prep_kernel<<<13312, 256, 0, stream>>>(dec, enc, decb, q_w, k_w, v_w, o_w, qwt, kvwt, owt);
    gemm_qkv_kernel<<<1280, 256, 0, stream>>>(encb, decb, kvwt, qwt, q_b, k_b, v_b, Qb, Kb, Vtb);
    attn_kernel<<<512, 256, 0, stream>>>(Qb, Kb, Vtb, emask, Xb);
    gemm_o_kernel<<<512, 256, 0, stream>>>(Xb, owt, o_b, out);
}